// Round 8
// baseline (315.253 us; speedup 1.0000x reference)
//
#include <hip/hip_runtime.h>

// Linear-RNN via pure GEMM decomposition (no per-step loop).
//   h_{t+1} = h_t@M + x̄_t@S ;  o_t = x̄_t·wod + h_t·woh
//   v_i = A_i @ W̃ ; o = A_i @ T + P_{i-1}@G ; P = scan(v, M^128 powers)
// R8: biggemm rewritten as LDS-staged K-chunk GEMM (global_load_lds w=16,
// XOR-swizzled ds_read_b128 fragments, k%4 wave partition + existing
// ksplit_reduce reused on the aliased staging LDS). All other kernels unchanged.

typedef __attribute__((ext_vector_type(8))) _Float16 half8;
typedef __attribute__((ext_vector_type(4))) float f32x4;
typedef unsigned short u16;

#define KTOT 2176   // 128*17
#define NBIG 640    // 512 V cols + 128 conv cols

__device__ __forceinline__ u16 f2h(float f) {
  union { _Float16 h; u16 u; } v; v.h = (_Float16)f; return v.u;
}
__device__ __forceinline__ float h2f(u16 u) {
  union { u16 u; _Float16 h; } v; v.u = u; return (float)v.h;
}

// async global->LDS, 16 B per lane; LDS dest = wave-uniform base + lane*16.
__device__ __forceinline__ void gld_lds16(const u16* g, u16* l) {
  __builtin_amdgcn_global_load_lds((const __attribute__((address_space(1))) void*)g,
                                   (__attribute__((address_space(3))) void*)l, 16, 0, 0);
}

// wave: 64x64 tile over kc in [kc0,kcN), software-pipelined (prefetch kc+1).
// A plain fp16 pre-offset to row0 (lda elems); Bt T32 pre-offset to col base.
__device__ __forceinline__ void wave_gemm(const u16* __restrict__ A, int lda,
                                          const u16* __restrict__ Bt, int nstr,
                                          int kc0, int kcN, int lane,
                                          f32x4 (&acc)[4][4]) {
  const int q = lane >> 4, l15 = lane & 15;
  #pragma unroll
  for (int rt = 0; rt < 4; ++rt)
    #pragma unroll
    for (int ct = 0; ct < 4; ++ct) { f32x4 z = {0.f,0.f,0.f,0.f}; acc[rt][ct] = z; }
  const u16* aP = A + (size_t)l15*lda + (size_t)kc0*32 + q*8;
  const u16* bP = Bt + ((size_t)kc0*nstr + l15)*32 + q*8;
  half8 a[4], b[4];
  #pragma unroll
  for (int rt = 0; rt < 4; ++rt) a[rt] = *(const half8*)(aP + (size_t)(rt*16)*lda);
  #pragma unroll
  for (int ct = 0; ct < 4; ++ct) b[ct] = *(const half8*)(bP + ct*512);
  for (int kc = kc0; kc < kcN; ++kc) {
    const u16* aN = aP + 32;
    const u16* bN = bP + (size_t)nstr*32;
    half8 an[4], bn[4];
    #pragma unroll
    for (int rt = 0; rt < 4; ++rt) an[rt] = *(const half8*)(aN + (size_t)(rt*16)*lda);
    #pragma unroll
    for (int ct = 0; ct < 4; ++ct) bn[ct] = *(const half8*)(bN + ct*512);
    #pragma unroll
    for (int rt = 0; rt < 4; ++rt)
      #pragma unroll
      for (int ct = 0; ct < 4; ++ct)
        acc[rt][ct] = __builtin_amdgcn_mfma_f32_16x16x32_f16(a[rt], b[ct], acc[rt][ct], 0,0,0);
    #pragma unroll
    for (int rt = 0; rt < 4; ++rt) a[rt] = an[rt];
    #pragma unroll
    for (int ct = 0; ct < 4; ++ct) b[ct] = bn[ct];
    aP = aN; bP = bN;
  }
}

// K-split reduce through LDS (48KB). Returns true for the epilogue wave (wid 0).
__device__ __forceinline__ bool ksplit_reduce(f32x4 (&acc)[4][4], float* red,
                                              int wid, int lane) {
  if (wid > 0) {
    float* dst = red + (wid - 1) * 4096;
    #pragma unroll
    for (int rt = 0; rt < 4; ++rt)
      #pragma unroll
      for (int ct = 0; ct < 4; ++ct)
        *(f32x4*)(dst + ((rt*4 + ct)*64 + lane)*4) = acc[rt][ct];
  }
  __syncthreads();
  if (wid > 0) return false;
  #pragma unroll
  for (int w = 0; w < 3; ++w)
    #pragma unroll
    for (int rt = 0; rt < 4; ++rt)
      #pragma unroll
      for (int ct = 0; ct < 4; ++ct)
        acc[rt][ct] += *(const f32x4*)(red + w*4096 + ((rt*4 + ct)*64 + lane)*4);
  return true;
}

// one 64x64 tile of a 512x512 squaring: (Mp_in @ Mt_in) -> Mp_out, Mt_out
__device__ __forceinline__ void square_tile(const u16* __restrict__ Mp_in,
                                            const u16* __restrict__ Mt_in,
                                            u16* __restrict__ Mp_out,
                                            u16* __restrict__ Mt_out,
                                            int bx, float* red, int tid) {
  const int wid = tid >> 6, lane = tid & 63, q = lane >> 4, l15 = lane & 15;
  int row0 = (bx >> 3) * 64, c0 = (bx & 7) * 64;
  f32x4 acc[4][4];
  wave_gemm(Mp_in + (size_t)row0*512, 512, Mt_in + (size_t)c0*32, 512,
            wid*4, wid*4 + 4, lane, acc);
  if (!ksplit_reduce(acc, red, wid, lane)) return;
  #pragma unroll
  for (int rt = 0; rt < 4; ++rt)
    for (int ct = 0; ct < 4; ++ct)
      for (int r = 0; r < 4; ++r) {
        int row = row0 + rt*16 + q*4 + r, col = c0 + ct*16 + l15;
        u16 v = f2h(acc[rt][ct][r]);
        Mp_out[row*512 + col] = v;
        Mt_out[(row>>5)*16384 + col*32 + (row&31)] = v;
      }
}

// ---- prep: M (plain+T32), S_r (+ Qs lag-0 seed), G col0, wod, hidden->fp16 ----
__global__ __launch_bounds__(256) void prep_kernel(
    const float* __restrict__ Wh, const float* __restrict__ Wo,
    const float* __restrict__ hidden,
    u16* __restrict__ Mp0, u16* __restrict__ Mt0,
    u16* __restrict__ Sr, float* __restrict__ G,
    float* __restrict__ wod, u16* __restrict__ Hf, u16* __restrict__ Qs) {
  int idx = blockIdx.x * 256 + threadIdx.x;
  if (idx < 262144) {                       // M[k][n] = Wh[n][16+k]
    int k = idx >> 9, n = idx & 511;
    u16 v = f2h(Wh[n*529 + 16 + k]);
    Mp0[k*512 + n] = v;
    Mt0[(k>>5)*16384 + n*32 + (k&31)] = v;
    return;
  }
  idx -= 262144;
  if (idx < 8704) {                         // S_r[q][n]; Qs lag-0 seed
    int q = idx >> 9, n = idx & 511;
    u16 v = f2h(Wh[n*529 + (q < 16 ? q : 528)]);
    Sr[idx] = v;
    Qs[idx] = v;
    return;
  }
  idx -= 8704;
  if (idx < 512) { G[idx*128 + 0] = Wo[16 + idx]; return; }
  idx -= 512;
  if (idx < 17) { wod[idx] = Wo[idx < 16 ? idx : 528]; return; }
  idx -= 17;
  if (idx < 131072) Hf[idx] = f2h(hidden[idx]);
}

// ---- level l (0..6): sq M^(2^l); Q lags [m,2m); G cols [m,2m); A-build filler ----
__global__ __launch_bounds__(256) void level_kernel(
    const u16* __restrict__ Mp_in, const u16* __restrict__ Mt_in,
    u16* __restrict__ Mp_out, u16* __restrict__ Mt_out,
    u16* __restrict__ Qs, float* __restrict__ G,
    const float* __restrict__ x, const float* __restrict__ cost,
    u16* __restrict__ A, int l) {
  __shared__ float red[12288];
  const int m = 1 << l;
  const int nq8 = (((17*m + 63) >> 6)) * 8;
  const int tid = threadIdx.x, bx = blockIdx.x;
  const int wid = tid >> 6, lane = tid & 63, q = lane >> 4, l15 = lane & 15;

  if (bx < 64) {  // square
    square_tile(Mp_in, Mt_in, Mp_out, Mt_out, bx, red, tid);
    return;
  }
  if (bx < 64 + nq8) {  // Q append: rows [0,17m) @ M^m -> [17m,34m)
    int bq = bx - 64;
    int row0 = (bq >> 3) * 64, c0 = (bq & 7) * 64;
    f32x4 acc[4][4];
    wave_gemm(Qs + (size_t)row0*512, 512, Mt_in + (size_t)c0*32, 512,
              wid*4, wid*4 + 4, lane, acc);
    if (!ksplit_reduce(acc, red, wid, lane)) return;
    int lim = 17*m;
    #pragma unroll
    for (int rt = 0; rt < 4; ++rt)
      for (int ct = 0; ct < 4; ++ct)
        for (int r = 0; r < 4; ++r) {
          int rowIn = row0 + rt*16 + q*4 + r, col = c0 + ct*16 + l15;
          if (rowIn < lim) Qs[(size_t)(lim + rowIn)*512 + col] = f2h(acc[rt][ct][r]);
        }
    return;
  }
  if (bx < 64 + nq8 + 32) {  // G append: G[:, m+c] = M^m @ G[:, c]
    int n0 = (bx - 64 - nq8) * 16;
    for (int idx = tid; idx < 16*m; idx += 256) {
      int c = idx & (m - 1), n = n0 + (idx >> l);
      const u16* mrow = Mp_in + n*512;
      float s0 = 0.f, s1 = 0.f, s2 = 0.f, s3 = 0.f;
      for (int k = 0; k < 512; k += 4) {
        s0 += h2f(mrow[k])   * G[k*128 + c];
        s1 += h2f(mrow[k+1]) * G[(k+1)*128 + c];
        s2 += h2f(mrow[k+2]) * G[(k+2)*128 + c];
        s3 += h2f(mrow[k+3]) * G[(k+3)*128 + c];
      }
      G[n*128 + m + c] = (s0 + s1) + (s2 + s3);
    }
    return;
  }
  // A-build filler: 293 WGs/level (l=6: 290), 2 rows each
  int abx = bx - (64 + nq8 + 32);
  int r = (l*293 + abx)*2 + (tid >> 7);
  if (r >= 4096) return;
  int s = tid & 127;
  int i = r >> 8, b = r & 255, t = i*128 + s;
  const float* xp = x + ((size_t)b*2048 + t)*16;
  u16* ap = A + (size_t)r*KTOT + s*17;
  #pragma unroll
  for (int p = 0; p < 16; p += 4) {
    float4 v = *(const float4*)(xp + p);
    ap[p] = f2h(v.x); ap[p+1] = f2h(v.y); ap[p+2] = f2h(v.z); ap[p+3] = f2h(v.w);
  }
  ap[16] = f2h(cost[(size_t)b*2048 + t]);
}

// ---- Cb[q][lam] = sum_k Sr[q][k] * G[k][lam] ----
__global__ void cbar_kernel(const u16* __restrict__ Sr, const float* __restrict__ G,
                            float* __restrict__ Cb) {
  int qq = blockIdx.x, lam = threadIdx.x;
  float s0 = 0.f, s1 = 0.f, s2 = 0.f, s3 = 0.f;
  for (int k = 0; k < 512; k += 4) {
    s0 += h2f(Sr[qq*512 + k])   * G[k*128 + lam];
    s1 += h2f(Sr[qq*512 + k+1]) * G[(k+1)*128 + lam];
    s2 += h2f(Sr[qq*512 + k+2]) * G[(k+2)*128 + lam];
    s3 += h2f(Sr[qq*512 + k+3]) * G[(k+3)*128 + lam];
  }
  Cb[qq*128 + lam] = (s0 + s1) + (s2 + s3);
}

// ---- build B (T32, 640 cols) + Gt (T32 of G) ----
__global__ void bbuild_kernel(const u16* __restrict__ Qs, const float* __restrict__ Cb,
                              const float* __restrict__ wod, const float* __restrict__ G,
                              u16* __restrict__ Bt, u16* __restrict__ Gt) {
  int idx = blockIdx.x * 256 + threadIdx.x;
  if (idx < KTOT * NBIG) {
    int krow = idx / NBIG, n = idx - krow * NBIG;
    int kc = krow >> 5, kk = krow & 31;
    int s = krow / 17, qq = krow - s * 17;
    u16 v;
    if (n < 512) {
      v = Qs[(size_t)((127 - s)*17 + qq)*512 + n];
    } else {
      int j = n - 512;
      if (s < j)       v = f2h(Cb[qq*128 + (j - 1 - s)]);
      else if (s == j) v = f2h(wod[qq]);
      else             v = 0;
    }
    Bt[(size_t)kc*(NBIG*32) + n*32 + kk] = v;
    return;
  }
  idx -= KTOT * NBIG;
  if (idx < 512*128) {
    int k = idx >> 7, j = idx & 127;
    Gt[(k>>5)*4096 + j*32 + (k&31)] = f2h(G[k*128 + j]);
  }
}

// ---- big GEMM [4096x640x2176], LDS-staged chunks of 128 k; +64 WGs square ----
__global__ __launch_bounds__(256) void biggemm_kernel(const u16* __restrict__ A,
                                                      const u16* __restrict__ Bt,
                                                      u16* __restrict__ V0,
                                                      float* __restrict__ out,
                                                      const u16* __restrict__ Mp7,
                                                      const u16* __restrict__ Mt7,
                                                      u16* __restrict__ Mp8,
                                                      u16* __restrict__ Mt8) {
  __shared__ float smem[12288];   // staging (32KB) aliased; red (48KB) after loop
  const int bx = blockIdx.x, tid = threadIdx.x;
  if (bx >= 640) { square_tile(Mp7, Mt7, Mp8, Mt8, bx - 640, smem, tid); return; }
  const int colg = bx >> 6, rowg = bx & 63;
  const int wid = tid >> 6, lane = tid & 63;
  const int q = lane >> 4, l15 = lane & 15;
  const int row0 = rowg*64, c0 = colg*64;
  u16* As = (u16*)smem;          // [64 rows][16 slots x 16B], slot ^= row&15
  u16* Bs = (u16*)smem + 8192;   // [4 kc][64 cols][4 slots x 16B], slot ^= (col>>2)&3

  const u16* gA[4]; u16* lA[4];
  const u16* gB[4]; u16* lB[4];
  #pragma unroll
  for (int j = 0; j < 4; ++j) {
    int rowA = (wid*4 + j)*4 + (lane >> 4);
    int pA = (lane & 15) ^ (rowA & 15);
    gA[j] = A + (size_t)(row0 + rowA)*KTOT + pA*8;
    lA[j] = As + (wid*4 + j)*512;
    int colB = j*16 + (lane >> 2);
    int qB = (lane & 3) ^ ((colB >> 2) & 3);
    gB[j] = Bt + ((size_t)wid*NBIG + c0 + colB)*32 + qB*8;
    lB[j] = Bs + wid*2048 + j*512;
  }
  const u16* aP[4]; const u16* bP[4];
  #pragma unroll
  for (int rt = 0; rt < 4; ++rt)
    aP[rt] = As + (rt*16 + l15)*128 + (((wid*4 + q) ^ l15) * 8);
  #pragma unroll
  for (int ct = 0; ct < 4; ++ct) {
    int col = ct*16 + l15;
    bP[ct] = Bs + wid*2048 + col*32 + ((q ^ ((l15 >> 2) & 3)) * 8);
  }

  f32x4 acc[4][4];
  #pragma unroll
  for (int rt = 0; rt < 4; ++rt)
    #pragma unroll
    for (int ct = 0; ct < 4; ++ct) { f32x4 z = {0.f,0.f,0.f,0.f}; acc[rt][ct] = z; }

  for (int c = 0; c < 17; ++c) {
    #pragma unroll
    for (int j = 0; j < 4; ++j) gld_lds16(gA[j], lA[j]);
    #pragma unroll
    for (int j = 0; j < 4; ++j) gld_lds16(gB[j], lB[j]);
    __syncthreads();             // vmcnt(0) drain: staged data visible
    half8 a[4], b[4];
    #pragma unroll
    for (int rt = 0; rt < 4; ++rt) a[rt] = *(const half8*)aP[rt];
    #pragma unroll
    for (int ct = 0; ct < 4; ++ct) b[ct] = *(const half8*)bP[ct];
    #pragma unroll
    for (int rt = 0; rt < 4; ++rt)
      #pragma unroll
      for (int ct = 0; ct < 4; ++ct)
        acc[rt][ct] = __builtin_amdgcn_mfma_f32_16x16x32_f16(a[rt], b[ct], acc[rt][ct], 0,0,0);
    __syncthreads();             // all ds_reads done before restage
    #pragma unroll
    for (int j = 0; j < 4; ++j) { gA[j] += 128; gB[j] += 4*NBIG*32; }
  }

  if (!ksplit_reduce(acc, smem, wid, lane)) return;
  #pragma unroll
  for (int rt = 0; rt < 4; ++rt)
    for (int ct = 0; ct < 4; ++ct)
      for (int r = 0; r < 4; ++r) {
        int rg = row0 + rt*16 + q*4 + r, col = c0 + ct*16 + l15;
        if (col < 512) {
          V0[(size_t)rg*512 + col] = f2h(acc[rt][ct][r]);
        } else {
          int j = col - 512, b = rg & 255, i = rg >> 8;
          out[(size_t)b*2048 + i*128 + j] = acc[rt][ct][r];
        }
      }
}

// ---- scan round: Vdst[i] = Vsrc[i-d]@M^(128d) + Vsrc[i]; i-d==-1 uses Hf.
//      bx>=512 (rounds 1,2 only): square next M-power for a later round. ----
__global__ __launch_bounds__(256) void scan_kernel(const u16* __restrict__ Vsrc,
                                                   u16* __restrict__ Vdst,
                                                   const u16* __restrict__ Mt,
                                                   const u16* __restrict__ Hf, int d,
                                                   const u16* __restrict__ Mp_si,
                                                   const u16* __restrict__ Mt_si,
                                                   u16* __restrict__ Mp_so,
                                                   u16* __restrict__ Mt_so) {
  __shared__ float red[12288];
  const int bx = blockIdx.x, tid = threadIdx.x;
  if (bx >= 512) { square_tile(Mp_si, Mt_si, Mp_so, Mt_so, bx - 512, red, tid); return; }
  int i = bx >> 5, rowg = (bx >> 3) & 3, colg = bx & 7;
  const int wid = tid >> 6, lane = tid & 63;
  const int q = lane >> 4, l15 = lane & 15;
  int row0 = rowg*64, c0 = colg*64;
  int src_i = i - d;
  if (src_i >= -1) {
    const u16* Asrc = (src_i >= 0) ? Vsrc + (size_t)(src_i*256 + row0)*512
                                   : Hf + (size_t)row0*512;
    f32x4 acc[4][4];
    wave_gemm(Asrc, 512, Mt + (size_t)c0*32, 512, wid*4, wid*4 + 4, lane, acc);
    if (!ksplit_reduce(acc, red, wid, lane)) return;
    #pragma unroll
    for (int rt = 0; rt < 4; ++rt)
      for (int ct = 0; ct < 4; ++ct)
        for (int r = 0; r < 4; ++r) {
          int rg = i*256 + row0 + rt*16 + q*4 + r, col = c0 + ct*16 + l15;
          Vdst[(size_t)rg*512 + col] = f2h(acc[rt][ct][r] + h2f(Vsrc[(size_t)rg*512 + col]));
        }
  } else {
    for (int it = tid; it < 512; it += 256) {
      int rl = it >> 3, cu = it & 7;
      size_t o = (size_t)(i*256 + row0 + rl)*512 + colg*64 + cu*8;
      *(uint4*)(Vdst + o) = *(const uint4*)(Vsrc + o);
    }
  }
}

// ---- final: out[b][i*128+j] += Pprev[(i,b)].g_j ; plus h_final = P_15 copy ----
__global__ __launch_bounds__(256) void final_kernel(const u16* __restrict__ V0,
                                                    const u16* __restrict__ Hf,
                                                    const u16* __restrict__ Gt,
                                                    float* __restrict__ out) {
  __shared__ float red[12288];
  const int bx = blockIdx.x, tid = threadIdx.x;
  if (bx >= 128) {  // h_final = P_15
    int idx = (bx - 128)*256 + tid;
    int base = idx * 8;
    int row = 3840 + (base >> 9), col = base & 511;
    const u16* vp = V0 + (size_t)row*512 + col;
    float* hp = out + 524288 + base;
    #pragma unroll
    for (int e = 0; e < 8; ++e) hp[e] = h2f(vp[e]);
    return;
  }
  int rowg = bx >> 1, colg = bx & 1;
  const int wid = tid >> 6, lane = tid & 63;
  const int q = lane >> 4, l15 = lane & 15;
  int row0 = rowg*64, c0 = colg*64;
  const u16* Abase = (row0 < 256) ? (Hf + (size_t)row0*512) : (V0 + (size_t)(row0-256)*512);
  f32x4 acc[4][4];
  wave_gemm(Abase, 512, Gt + (size_t)c0*32, 128, wid*4, wid*4 + 4, lane, acc);
  if (!ksplit_reduce(acc, red, wid, lane)) return;
  #pragma unroll
  for (int rt = 0; rt < 4; ++rt)
    for (int ct = 0; ct < 4; ++ct)
      for (int r = 0; r < 4; ++r) {
        int rg = row0 + rt*16 + q*4 + r, j = c0 + ct*16 + l15;
        int b = rg & 255, i = rg >> 8;
        out[(size_t)b*2048 + i*128 + j] += acc[rt][ct][r];
      }
}

extern "C" void kernel_launch(void* const* d_in, const int* in_sizes, int n_in,
                              void* d_out, int out_size, void* d_ws, size_t ws_size,
                              hipStream_t stream) {
  (void)in_sizes; (void)n_in; (void)out_size; (void)ws_size;
  const float* x      = (const float*)d_in[0];
  const float* hidden = (const float*)d_in[1];
  const float* cost   = (const float*)d_in[2];
  const float* Wo     = (const float*)d_in[3];
  const float* Wh     = (const float*)d_in[4];
  float* out = (float*)d_out;
  char* ws = (char*)d_ws;

  auto Mp = [&](int l){ return (u16*)(ws + (size_t)l*524288); };
  auto Mt = [&](int l){ return (u16*)(ws + 5767168 + (size_t)l*524288); };
  u16*   Qs  = (u16*)(ws + 11534336);   // 2176 x 512
  float* G   = (float*)(ws + 13762560); // 512 x 128
  u16*   Sr  = (u16*)(ws + 14024704);   // 17 x 512
  float* wod = (float*)(ws + 14057472); // 17
  float* Cb  = (float*)(ws + 14057728); // 17 x 128
  u16*   Hf  = (u16*)(ws + 14074112);   // 256 x 512
  u16*   Bt  = (u16*)(ws + 14336256);   // T32 2176 x 640
  u16*   Gt  = (u16*)(ws + 17121536);   // T32 512 x 128
  u16*   A   = (u16*)(ws + 17252608);   // 4096 x 2176
  u16*   V0  = (u16*)(ws + 35078400);   // 4096 x 512
  u16*   V1  = (u16*)(ws + 39272704);   // 4096 x 512

  prep_kernel<<<1573, 256, 0, stream>>>(Wh, Wo, hidden, Mp(0), Mt(0), Sr, G, wod, Hf, Qs);
  for (int l = 0; l <= 6; ++l) {
    int m = 1 << l;
    int nq8 = ((17*m + 63) >> 6) * 8;
    int abn = (l == 6) ? 290 : 293;
    int grid = 64 + nq8 + 32 + abn;
    level_kernel<<<grid, 256, 0, stream>>>(Mp(l), Mt(l), Mp(l+1), Mt(l+1),
                                           Qs, G, x, cost, A, l);
  }
  cbar_kernel<<<17, 128, 0, stream>>>(Sr, G, Cb);
  bbuild_kernel<<<(KTOT*NBIG + 512*128 + 255)/256, 256, 0, stream>>>(Qs, Cb, wod, G, Bt, Gt);
  // biggemm + square M^128->M^256
  biggemm_kernel<<<704, 256, 0, stream>>>(A, Bt, V0, out, Mp(7), Mt(7), Mp(8), Mt(8));
  // scan1 (d=1, M^128) + square M^256->M^512
  scan_kernel<<<576, 256, 0, stream>>>(V0, V1, Mt(7), Hf, 1, Mp(8), Mt(8), Mp(9), Mt(9));
  // scan2 (d=2, M^256) + square M^512->M^1024
  scan_kernel<<<576, 256, 0, stream>>>(V1, V0, Mt(8), Hf, 2, Mp(9), Mt(9), Mp(10), Mt(10));
  scan_kernel<<<512, 256, 0, stream>>>(V0, V1, Mt(9), Hf, 4, Mp(10), Mt(10), Mp(10), Mt(10));
  scan_kernel<<<512, 256, 0, stream>>>(V1, V0, Mt(10), Hf, 8, Mp(10), Mt(10), Mp(10), Mt(10));
  final_kernel<<<192, 256, 0, stream>>>(V0, Hf, Gt, out);
}